// Round 4
// baseline (87.214 us; speedup 1.0000x reference)
//
#include <hip/hip_runtime.h>
#include <stdint.h>

#define IN_F   1024
#define OUT_F  512
#define BATCH  256

// ---------------------------------------------------------------------------
// FUSED single-launch kernel (A/B test: node-overhead hypothesis).
// Round-2 evidence: 30% VALU cut in reduce -> only -2.2% total. Model says our
// GPU work is ~6 us while dur_us ~77; suspect ~10 us/graph-node overhead x3
// nodes (harness 256MiB poison fill + 2 kernels). This version = ONE node.
//
// Round-3 fix: mask words read from LDS are per-lane VGPR values -> LLVM could
// not honor the "s" (SGPR-pair) constraint on v_cndmask_b32. Masks are now
// made explicitly wave-uniform via readfirstlane on both 32-bit halves after
// the LDS broadcast read (HK's readfirstlane-to-SGPR hoisting pattern).
//
// Grid: 256 blocks x 512 threads (1 block/CU). Block = (oq = o-quad 0..127,
// bh = b-half 0..1).
// Phase 1: block computes edge masks for its 4 o-rows via ballot -> LDS.
//   word W = s*16 + c*4 + j  (s = o sub-index, c = i-chunk, j = float4 slot);
//   bit l <=> EDGE at i = c*256 + 4*l + j.  EXACT same numerics as the
//   verified 2-kernel version (absmax=0): f32 op sequence with correctly-
//   rounded double log; predicate !(t1 > t0) (argmax tie -> edge).
// Phase 2: per c-chunk, pull 16 mask words LDS -> SGPR pairs, then the
//   round-2 csel/min3|max3 reduce. Mixed-parity o-quad handled straight-line
//   (s even = min/2.0f, s odd = max/-1.0f; s is compile-time -> no
//   divergence). Pair-merged butterfly: lo 32 lanes finish b0, hi 32 lanes
//   b1; lane 0 / lane 32 write float4 (4 consecutive o's) to out.
// ---------------------------------------------------------------------------
__device__ __forceinline__ float csel(unsigned long long m, float xv, float sent) {
    // r = bit_lane(m) ? xv : sent   -- one v_cndmask_b32 (VOP3, sgpr-pair mask)
    float r;
    asm("v_cndmask_b32 %0, %1, %2, %3" : "=v"(r) : "v"(sent), "v"(xv), "s"(m));
    return r;
}
__device__ __forceinline__ float vmin3(float a, float b, float c) {
    float r;
    asm("v_min3_f32 %0, %1, %2, %3" : "=v"(r) : "v"(a), "v"(b), "v"(c));
    return r;
}
__device__ __forceinline__ float vmax3(float a, float b, float c) {
    float r;
    asm("v_max3_f32 %0, %1, %2, %3" : "=v"(r) : "v"(a), "v"(b), "v"(c));
    return r;
}
// LDS u64 -> wave-uniform SGPR-pair-eligible u64
__device__ __forceinline__ unsigned long long uniform_u64(unsigned long long m) {
    unsigned int lo = __builtin_amdgcn_readfirstlane((unsigned int)m);
    unsigned int hi = __builtin_amdgcn_readfirstlane((unsigned int)(m >> 32));
    return ((unsigned long long)hi << 32) | lo;
}

__global__ __launch_bounds__(512, 2) void fused_kernel(
    const float* __restrict__ x,    // [BATCH, IN_F]
    const float* __restrict__ etc,  // [OUT_F, IN_F, 2]
    const float* __restrict__ un,   // [OUT_F, IN_F, 2]
    float* __restrict__ out)        // [BATCH, OUT_F]
{
    __shared__ unsigned long long lmask[64];   // [s*16 + c*4 + j]

    int oq   = __builtin_amdgcn_readfirstlane(blockIdx.x >> 1);  // 0..127
    int bh   = __builtin_amdgcn_readfirstlane(blockIdx.x & 1);   // 0..1
    int wv   = threadIdx.x >> 6;   // wave 0..7
    int lane = threadIdx.x & 63;

    // ---------------- phase 1: masks for o = oq*4 + 0..3 ----------------
    // wave wv owns words W = wv*8 .. wv*8+7 (8 ballots, 32 f64 logs/lane)
    #pragma unroll
    for (int k = 0; k < 8; ++k) {
        int W = wv * 8 + k;            // wave-uniform
        int s = W >> 4;
        int c = (W >> 2) & 3;
        int j = W & 3;
        int o = oq * 4 + s;
        int i = c * 256 + lane * 4 + j;
        int p = o * IN_F + i;

        float2 e = ((const float2*)etc)[p];
        float2 u = ((const float2*)un)[p];

        float s0 = u.x + 1e-10f;
        float l0 = (float)log((double)s0);
        float m0 = -l0 + 1e-10f;
        float g0 = -(float)log((double)m0);
        float t0 = e.x + g0;

        float s1 = u.y + 1e-10f;
        float l1 = (float)log((double)s1);
        float m1 = -l1 + 1e-10f;
        float g1 = -(float)log((double)m1);
        float t1 = e.y + g1;

        unsigned long long bits = __ballot(!(t1 > t0));   // 1 = edge
        if (lane == 0) lmask[W] = bits;
    }
    __syncthreads();

    // ---------------- phase 2: reduce 8 b-pairs per wave ----------------
    const float4* xq = (const float4*)x;
    bool hi = (lane & 32) != 0;
    int obase = oq * 4;

    for (int tile = 0; tile < 2; ++tile) {
        // 4 b-pairs this tile; bp in 0..127 globally
        int bp0 = (bh << 6) + (wv << 3) + (tile << 2);

        float acc[4][4][2];   // [q = bp-in-tile][s = o sub][b in pair]
        #pragma unroll
        for (int q = 0; q < 4; ++q)
            #pragma unroll
            for (int s = 0; s < 4; ++s) {
                float S = (s & 1) ? -1.0f : 2.0f;
                acc[q][s][0] = S;
                acc[q][s][1] = S;
            }

        #pragma unroll
        for (int c = 0; c < 4; ++c) {
            // 16 mask words for this c (4 o's x 4 j): LDS broadcast ->
            // readfirstlane'd to wave-uniform (SGPR-pair eligible) values
            unsigned long long mk[16];
            #pragma unroll
            for (int s = 0; s < 4; ++s)
                #pragma unroll
                for (int j = 0; j < 4; ++j)
                    mk[s * 4 + j] = uniform_u64(lmask[s * 16 + c * 4 + j]);

            #pragma unroll
            for (int q = 0; q < 4; ++q) {
                int b0 = (bp0 + q) << 1;
                float4 va = xq[(b0 + 0) * (IN_F / 4) + c * 64 + lane];
                float4 vb = xq[(b0 + 1) * (IN_F / 4) + c * 64 + lane];
                #pragma unroll
                for (int s = 0; s < 4; ++s) {
                    float S = (s & 1) ? -1.0f : 2.0f;
                    float e0a = csel(mk[s*4+0], va.x, S);
                    float e1a = csel(mk[s*4+1], va.y, S);
                    float e2a = csel(mk[s*4+2], va.z, S);
                    float e3a = csel(mk[s*4+3], va.w, S);
                    float e0b = csel(mk[s*4+0], vb.x, S);
                    float e1b = csel(mk[s*4+1], vb.y, S);
                    float e2b = csel(mk[s*4+2], vb.z, S);
                    float e3b = csel(mk[s*4+3], vb.w, S);
                    if (s & 1) {
                        acc[q][s][0] = vmax3(acc[q][s][0], vmax3(e0a, e1a, e2a), e3a);
                        acc[q][s][1] = vmax3(acc[q][s][1], vmax3(e0b, e1b, e2b), e3b);
                    } else {
                        acc[q][s][0] = vmin3(acc[q][s][0], vmin3(e0a, e1a, e2a), e3a);
                        acc[q][s][1] = vmin3(acc[q][s][1], vmin3(e0b, e1b, e2b), e3b);
                    }
                }
            }
        }

        // butterflies + stores: lo half finishes b0, hi half b1
        #pragma unroll
        for (int q = 0; q < 4; ++q) {
            int b0 = (bp0 + q) << 1;
            float z[4];
            #pragma unroll
            for (int s = 0; s < 4; ++s) {
                float aA = acc[q][s][0], aB = acc[q][s][1];
                float cr = hi ? aA : aB;            // expose partner's value
                float pp = __shfl_xor(cr, 32, 64);  // full-wave shuffle
                float zz = hi ? aB : aA;
                if (s & 1) {
                    zz = fmaxf(zz, pp);
                    #pragma unroll
                    for (int d = 16; d; d >>= 1) zz = fmaxf(zz, __shfl_xor(zz, d, 64));
                } else {
                    zz = fminf(zz, pp);
                    #pragma unroll
                    for (int d = 16; d; d >>= 1) zz = fminf(zz, __shfl_xor(zz, d, 64));
                }
                z[s] = zz;
            }
            if ((lane & 31) == 0) {
                int b = b0 + (lane >> 5);
                float4 o4 = make_float4(z[0], z[1], z[2], z[3]);
                *((float4*)(out + b * OUT_F + obase)) = o4;
            }
        }
    }
}

extern "C" void kernel_launch(void* const* d_in, const int* in_sizes, int n_in,
                              void* d_out, int out_size, void* d_ws, size_t ws_size,
                              hipStream_t stream) {
    const float* x   = (const float*)d_in[0];  // [BATCH, IN_F]
    const float* etc = (const float*)d_in[1];  // [OUT_F, IN_F, 2]
    const float* un  = (const float*)d_in[2];  // [OUT_F, IN_F, 2]
    float* out = (float*)d_out;                // [BATCH, OUT_F]
    (void)d_ws; (void)ws_size;                 // workspace no longer needed

    // ONE node: 256 blocks x 512 threads (1 block/CU, masks self-computed)
    hipLaunchKernelGGL(fused_kernel, dim3(256), dim3(512), 0, stream,
                       x, etc, un, out);
}

// Round 5
// 77.331 us; speedup vs baseline: 1.1278x; 1.1278x over previous
//
#include <hip/hip_runtime.h>
#include <stdint.h>

#define IN_F   1024
#define OUT_F  512
#define BATCH  256

// ---------------------------------------------------------------------------
// Kernel A (UNCHANGED, proven absmax=0): per (o,i) decide EDGE (argmax idx 0)
// vs NO_EDGE, pack via ballot. Deinterleaved-by-4 layout:
//   mask_t[o*16 + c*4 + j], bit l  <=>  EDGE at i = c*256 + 4*l + j
// f32 op sequence with correctly-rounded double log; EDGE = !(t1 > t0).
// ---------------------------------------------------------------------------
__global__ __launch_bounds__(256) void mask_kernel(
    const float* __restrict__ etc,          // [OUT_F, IN_F, 2]
    const float* __restrict__ un,           // [OUT_F, IN_F, 2]
    unsigned long long* __restrict__ mask_t)// [OUT_F * 16]
{
    int o = blockIdx.x >> 2;
    int c = blockIdx.x & 3;
    int j = threadIdx.x >> 6;   // wave id = sub-position within float4
    int l = threadIdx.x & 63;   // lane = bit position
    int i = c * 256 + l * 4 + j;
    int p = o * IN_F + i;

    float2 e = ((const float2*)etc)[p];
    float2 u = ((const float2*)un)[p];

    float s0 = u.x + 1e-10f;
    float l0 = (float)log((double)s0);
    float m0 = -l0 + 1e-10f;
    float g0 = -(float)log((double)m0);
    float t0 = e.x + g0;

    float s1 = u.y + 1e-10f;
    float l1 = (float)log((double)s1);
    float m1 = -l1 + 1e-10f;
    float g1 = -(float)log((double)m1);
    float t1 = e.y + g1;

    unsigned long long bits = __ballot(!(t1 > t0));   // 1 = edge
    if (l == 0) mask_t[o * 16 + c * 4 + j] = bits;
}

// ---------------------------------------------------------------------------
// Kernel B: out[b,o] = reduce_i (edge ? x[b,i] : offset), acc init = offset.
//
// Round-5 change vs round-2 (which measured 77.3 us total): 8 o's per wave
// instead of 4 (wave count 16384 -> 8192). Total VALU is unchanged (every
// (b,o,i) visited once at 2 ops: csel + min3-slot), but each x row is now
// shared across 8 outputs -> L2 x-traffic halves (134 MB -> 67 MB), which was
// on par with the VALU floor. Masks remain wave-uniform GLOBAL scalar loads
// (readfirstlane'd o-group -> provably uniform -> "s"-constraint OK; the LDS
// variant of round 3 broke this). Mixed parity in the o-octet is straight-line
// unrolled: s is compile-time, s even = min/sentinel 2.0, s odd = max/-1.0
// (this exact pattern passed absmax=0 in round 4's fused kernel).
// Pair-merged butterfly: lo 32 lanes finish b0, hi 32 lanes b1; lanes 0/32
// store two float4s (8 consecutive o's).
// ---------------------------------------------------------------------------
__device__ __forceinline__ float csel(unsigned long long m, float xv, float sent) {
    // r = bit_lane(m) ? xv : sent   -- one v_cndmask_b32 (VOP3, sgpr-pair mask)
    float r;
    asm("v_cndmask_b32 %0, %1, %2, %3" : "=v"(r) : "v"(sent), "v"(xv), "s"(m));
    return r;
}
__device__ __forceinline__ float vmin3(float a, float b, float c) {
    float r;
    asm("v_min3_f32 %0, %1, %2, %3" : "=v"(r) : "v"(a), "v"(b), "v"(c));
    return r;
}
__device__ __forceinline__ float vmax3(float a, float b, float c) {
    float r;
    asm("v_max3_f32 %0, %1, %2, %3" : "=v"(r) : "v"(a), "v"(b), "v"(c));
    return r;
}

__global__ __launch_bounds__(256, 8) void reduce_kernel(
    const float* __restrict__ x,                   // [BATCH, IN_F]
    const unsigned long long* __restrict__ mask_t, // [OUT_F * 16]
    float* __restrict__ out)                       // [BATCH, OUT_F]
{
    int wave = threadIdx.x >> 6;
    int lane = threadIdx.x & 63;
    int T  = blockIdx.x * 4 + wave;                    // 8192 wave-tasks
    int bp = __builtin_amdgcn_readfirstlane(T >> 6);   // b-pair 0..127
    int og = __builtin_amdgcn_readfirstlane(T & 63);   // o-octet 0..63

    const float4* xA = (const float4*)(x + (bp * 2 + 0) * IN_F);
    const float4* xB = (const float4*)(x + (bp * 2 + 1) * IN_F);

    int ob = og * 8;                                   // 8 consecutive o's
    const unsigned long long* mw = mask_t + ob * 16;   // row s at mw + s*16

    bool hi = (lane & 32) != 0;

    float accA[8], accB[8];
    #pragma unroll
    for (int s = 0; s < 8; ++s) {
        float S = (s & 1) ? -1.0f : 2.0f;
        accA[s] = S;
        accB[s] = S;
    }

    #pragma unroll
    for (int c = 0; c < 4; ++c) {
        float4 va = xA[c * 64 + lane];
        float4 vb = xB[c * 64 + lane];
        #pragma unroll
        for (int s = 0; s < 8; ++s) {
            // wave-uniform global scalar loads -> SGPR pairs
            unsigned long long m0 = mw[s * 16 + c * 4 + 0];
            unsigned long long m1 = mw[s * 16 + c * 4 + 1];
            unsigned long long m2 = mw[s * 16 + c * 4 + 2];
            unsigned long long m3 = mw[s * 16 + c * 4 + 3];
            float S = (s & 1) ? -1.0f : 2.0f;
            float e0a = csel(m0, va.x, S);
            float e1a = csel(m1, va.y, S);
            float e2a = csel(m2, va.z, S);
            float e3a = csel(m3, va.w, S);
            float e0b = csel(m0, vb.x, S);
            float e1b = csel(m1, vb.y, S);
            float e2b = csel(m2, vb.z, S);
            float e3b = csel(m3, vb.w, S);
            if (s & 1) {
                accA[s] = vmax3(accA[s], vmax3(e0a, e1a, e2a), e3a);
                accB[s] = vmax3(accB[s], vmax3(e0b, e1b, e2b), e3b);
            } else {
                accA[s] = vmin3(accA[s], vmin3(e0a, e1a, e2a), e3a);
                accB[s] = vmin3(accB[s], vmin3(e0b, e1b, e2b), e3b);
            }
        }
    }

    // branchless pair-merge + single 5-step half-butterfly per output
    float z[8];
    #pragma unroll
    for (int s = 0; s < 8; ++s) {
        float cr = hi ? accA[s] : accB[s];     // expose partner's value
        float pp = __shfl_xor(cr, 32, 64);     // full-wave shuffle
        float zz = hi ? accB[s] : accA[s];
        if (s & 1) {
            zz = fmaxf(zz, pp);
            #pragma unroll
            for (int d = 16; d; d >>= 1) zz = fmaxf(zz, __shfl_xor(zz, d, 64));
        } else {
            zz = fminf(zz, pp);
            #pragma unroll
            for (int d = 16; d; d >>= 1) zz = fminf(zz, __shfl_xor(zz, d, 64));
        }
        z[s] = zz;
    }

    if ((lane & 31) == 0) {
        int b = bp * 2 + (lane >> 5);
        float* ob_ptr = out + b * OUT_F + ob;
        *((float4*)(ob_ptr + 0)) = make_float4(z[0], z[1], z[2], z[3]);
        *((float4*)(ob_ptr + 4)) = make_float4(z[4], z[5], z[6], z[7]);
    }
}

extern "C" void kernel_launch(void* const* d_in, const int* in_sizes, int n_in,
                              void* d_out, int out_size, void* d_ws, size_t ws_size,
                              hipStream_t stream) {
    const float* x   = (const float*)d_in[0];  // [BATCH, IN_F]
    const float* etc = (const float*)d_in[1];  // [OUT_F, IN_F, 2]
    const float* un  = (const float*)d_in[2];  // [OUT_F, IN_F, 2]
    float* out = (float*)d_out;                // [BATCH, OUT_F]
    unsigned long long* mask_t = (unsigned long long*)d_ws;  // 64 KB

    // Kernel A: one block per (o, 256-i chunk)
    hipLaunchKernelGGL(mask_kernel, dim3(OUT_F * 4), dim3(256), 0, stream,
                       etc, un, mask_t);
    // Kernel B: 8192 wave-tasks (2 b-rows x 8 consecutive o's), 4 waves/block
    hipLaunchKernelGGL(reduce_kernel, dim3(BATCH * OUT_F / 16 / 4), dim3(256), 0, stream,
                       x, mask_t, out);
}